// Round 25
// baseline (103.705 us; speedup 1.0000x reference)
//
#include <hip/hip_runtime.h>

constexpr int Bn = 8, Cn = 3, Hn = 720, Wn = 1280;
constexpr int HW = Hn * Wn;                    // 921600 px per image
constexpr long long NTOT = (long long)Bn * Cn * HW;

constexpr int BLK  = 256;
constexpr int TH   = 16, TW = 64;              // output tile 16x64 (4 rows per wave)
constexpr int TCOL = Wn / TW;                  // 20 tile-cols
constexpr int TPI  = (Hn / TH) * TCOL;         // 900 tiles per image
constexpr int NWG  = 8 * TPI;                  // 7200 blocks; bid&7 = image/XCD
constexpr int PXT  = 4;                        // 4 px per lane (one 4-row wave strip)
constexpr int WRW  = 12;                       // wave window rows: YW-4 .. YW+7
constexpr int WCW  = 84;                       // window cols: XS-4 .. XS+79
constexpr int F4WW = WCW / 4;                  // 21 f4 per window row
constexpr int F4PW = WRW * F4WW;               // 252 f4 slots per plane
constexpr int NF4W = 2 * F4PW;                 // 504 slots per wave per channel
constexpr int PSEW = 1024;                     // bf16 plane stride (elements)
constexpr int WBUF = 2 * PSEW;                 // 2048 bf16 = 4 KB per wave buffer

typedef float f4 __attribute__((ext_vector_type(4)));

__device__ __forceinline__ float bf(unsigned short h) {
    return __uint_as_float((unsigned)h << 16);
}

// 4 f32 -> 4 bf16 (RNE) -> one 8B LDS write
__device__ __forceinline__ void put8(unsigned short* dst, f4 v) {
    unsigned r0, r1;
    asm("v_cvt_pk_bf16_f32 %0, %1, %2" : "=v"(r0) : "v"(v[0]), "v"(v[1]));
    asm("v_cvt_pk_bf16_f32 %0, %1, %2" : "=v"(r1) : "v"(v[2]), "v"(v[3]));
    uint2 u; u.x = r0; u.y = r1;
    *reinterpret_cast<uint2*>(dst) = u;
}

__global__ __launch_bounds__(256) void warp_loss_kernel(
        const float* __restrict__ L, const float* __restrict__ R,
        const float* __restrict__ Flm, const float* __restrict__ Frm,
        const float* __restrict__ G, float* __restrict__ part) {
    // BARRIER-FREE waves: each wave owns 4 output rows + a private 12x84
    // bf16 window pair (double-buffered). Wave-local ds_write->ds_read is
    // ordered by lgkmcnt, so the channel loop has ZERO __syncthreads —
    // no 4-wave convoy at channel boundaries (the invariant feature of the
    // six variants pinned at ~86us). LDS exactly 32KB -> 5 blocks/CU.
    const int b    = blockIdx.x & 7;
    const int t    = blockIdx.x >> 3;          // [0, 900)
    const int trow = t / TCOL;
    const int tcol = t - trow * TCOL;
    const int Y    = trow * TH;
    const int XS   = tcol * TW;
    const int tid  = (int)threadIdx.x;
    const int wid  = tid >> 6;
    const int lane = tid & 63;
    const int YW   = Y + 4 * wid;              // wave's first output row

    const float* __restrict__ Lb = L + (size_t)b * Cn * HW;
    const float* __restrict__ Rb = R + (size_t)b * Cn * HW;
    const float* __restrict__ Gb = G + (size_t)b * Cn * HW;
    const float* __restrict__ fl = Flm + (size_t)b * 2 * HW;  // [0,HW)=x, [HW,2HW)=y
    const float* __restrict__ fr = Frm + (size_t)b * 2 * HW;

    __shared__ unsigned short win[2][4][WBUF]; // 32 KB exactly: [buf][wave][win]
    // wsum lives in a never-written pad corner (elements 2040..2047 of
    // win[1][3]; staging max dstE=2031, sampling max read 2032) -> no extra LDS.
    float* const wsf = reinterpret_cast<float*>(&win[1][3][2040]);

    // ---- wave-private staging geometry (channel-invariant); 8 slots/lane ----
    int soff[8], dstE[8];
    #pragma unroll
    for (int r = 0; r < 8; ++r) {
        const int s  = min(r * 64 + lane, NF4W - 1);   // tail lanes duplicate
        const int pl = (s >= F4PW) ? 1 : 0;
        const int f  = s - pl * F4PW;
        const int wr = f / F4WW;
        const int c4 = f - wr * F4WW;
        const int ys = min(max(YW - 4 + wr, 0), Hn - 1);
        const int xw = min(max(XS - 4 + c4 * 4, 0), Wn - 4);  // 16B-aligned
        soff[r] = ys * Wn + xw;
        dstE[r] = pl * PSEW + wr * WCW + c4 * 4;
    }

    // ---- prologue: issue ch0 staging (8 f4), taps overlap, write, NO barrier ----
    f4 s0, s1, s2, s3, s4, s5, s6, s7;
    #define LDS_SRC(k, Lc, Rc) \
        (*reinterpret_cast<const f4*>(((dstE[k] >= PSEW) ? (Rc) : (Lc)) + soff[k]))
    s0 = LDS_SRC(0, Lb, Rb); s1 = LDS_SRC(1, Lb, Rb);
    s2 = LDS_SRC(2, Lb, Rb); s3 = LDS_SRC(3, Lb, Rb);
    s4 = LDS_SRC(4, Lb, Rb); s5 = LDS_SRC(5, Lb, Rb);
    s6 = LDS_SRC(6, Lb, Rb); s7 = LDS_SRC(7, Lb, Rb);

    // ---- per-px tap state (channel-invariant); px k = (YW+k, XS+lane) ----
    int   aL[PXT], aR[PXT];
    float lwx[PXT], lwy[PXT], rwx[PXT], rwy[PXT];
    #pragma unroll
    for (int k = 0; k < PXT; ++k) {
        const int y = YW + k, x = XS + lane;
        const int p = y * Wn + x;
        {
            const float fx = fminf(fmaxf(fl[p],      -4.0f), 3.99951171875f);
            const float fy = fminf(fmaxf(fl[HW + p], -4.0f), 3.99951171875f);
            const float xc = fminf(fmaxf((float)x + fx, 0.f), (float)(Wn - 1));
            const float yc = fminf(fmaxf((float)y + fy, 0.f), (float)(Hn - 1));
            const float x0f = floorf(xc), y0f = floorf(yc);
            lwx[k] = xc - x0f;  lwy[k] = yc - y0f;
            aL[k] = ((int)y0f - (YW - 4)) * WCW + ((int)x0f - (XS - 4));
        }
        {
            const float fx = fminf(fmaxf(fr[p],      -4.0f), 3.99951171875f);
            const float fy = fminf(fmaxf(fr[HW + p], -4.0f), 3.99951171875f);
            const float xc = fminf(fmaxf((float)x + fx, 0.f), (float)(Wn - 1));
            const float yc = fminf(fmaxf((float)y + fy, 0.f), (float)(Hn - 1));
            const float x0f = floorf(xc), y0f = floorf(yc);
            rwx[k] = xc - x0f;  rwy[k] = yc - y0f;
            aR[k] = PSEW + ((int)y0f - (YW - 4)) * WCW + ((int)x0f - (XS - 4));
        }
    }

    unsigned short* const w0b = &win[0][wid][0];
    unsigned short* const w1b = &win[1][wid][0];
    put8(&w0b[dstE[0]], s0); put8(&w0b[dstE[1]], s1);
    put8(&w0b[dstE[2]], s2); put8(&w0b[dstE[3]], s3);
    put8(&w0b[dstE[4]], s4); put8(&w0b[dstE[5]], s5);
    put8(&w0b[dstE[6]], s6); put8(&w0b[dstE[7]], s7);
    // no barrier: this wave wrote it, this wave reads it (lgkmcnt orders)

    float local = 0.f;

    #pragma unroll
    for (int c = 0; c < Cn; ++c) {
        // (1) gt loads for this channel FIRST (older in vmcnt FIFO)
        float g[PXT];
        #pragma unroll
        for (int k = 0; k < PXT; ++k)
            g[k] = Gb[(size_t)c * HW + (YW + k) * Wn + XS + lane];

        // (2) issue next channel's staging loads (span the sample phase)
        if (c < Cn - 1) {
            const float* __restrict__ Lc = Lb + (size_t)(c + 1) * HW;
            const float* __restrict__ Rc = Rb + (size_t)(c + 1) * HW;
            s0 = LDS_SRC(0, Lc, Rc); s1 = LDS_SRC(1, Lc, Rc);
            s2 = LDS_SRC(2, Lc, Rc); s3 = LDS_SRC(3, Lc, Rc);
            s4 = LDS_SRC(4, Lc, Rc); s5 = LDS_SRC(5, Lc, Rc);
            s6 = LDS_SRC(6, Lc, Rc); s7 = LDS_SRC(7, Lc, Rc);
        }

        // (3) sample channel c from this wave's buffer (pure LDS + VALU)
        const unsigned short* __restrict__ w = (c & 1) ? w1b : w0b;
        #pragma unroll
        for (int k = 0; k < PXT; ++k) {
            const int a = aL[k];
            const float v00 = bf(w[a]),       v01 = bf(w[a + 1]);
            const float v10 = bf(w[a + WCW]), v11 = bf(w[a + WCW + 1]);
            float top = fmaf(lwx[k], v01 - v00, v00);
            float bot = fmaf(lwx[k], v11 - v10, v10);
            const float sL = fmaf(lwy[k], bot - top, top);
            const int a2 = aR[k];
            const float u00 = bf(w[a2]),       u01 = bf(w[a2 + 1]);
            const float u10 = bf(w[a2 + WCW]), u11 = bf(w[a2 + WCW + 1]);
            top = fmaf(rwx[k], u01 - u00, u00);
            bot = fmaf(rwx[k], u11 - u10, u10);
            const float sR = fmaf(rwy[k], bot - top, top);
            local += fabsf(sL - g[k]) + fabsf(sR - g[k]);
        }

        // (4) write next channel into the other private buffer; NO barrier
        if (c < Cn - 1) {
            unsigned short* const wd = ((c + 1) & 1) ? w1b : w0b;
            put8(&wd[dstE[0]], s0); put8(&wd[dstE[1]], s1);
            put8(&wd[dstE[2]], s2); put8(&wd[dstE[3]], s3);
            put8(&wd[dstE[4]], s4); put8(&wd[dstE[5]], s5);
            put8(&wd[dstE[6]], s6); put8(&wd[dstE[7]], s7);
        }
    }

    // wave(64) shuffle reduce -> pad-corner wsum -> one plain store per block
    #pragma unroll
    for (int off = 32; off > 0; off >>= 1)
        local += __shfl_down(local, off, 64);

    if (lane == 0) wsf[wid] = local;   // wave 3's pad corner, never staged/sampled
    __syncthreads();                   // the ONLY block barrier
    if (tid == 0)
        part[blockIdx.x] = wsf[0] + wsf[1] + wsf[2] + wsf[3];
}

__global__ __launch_bounds__(256) void finalize_kernel(
        const float* __restrict__ part, float* __restrict__ out) {
    double s = 0.0;
    for (int i = (int)threadIdx.x; i < NWG; i += 256)
        s += (double)part[i];
    #pragma unroll
    for (int off = 32; off > 0; off >>= 1)
        s += __shfl_down(s, off, 64);
    __shared__ double ws[4];
    const int lane = threadIdx.x & 63;
    const int wid  = threadIdx.x >> 6;
    if (lane == 0) ws[wid] = s;
    __syncthreads();
    if (threadIdx.x == 0)
        out[0] = (float)((ws[0] + ws[1] + ws[2] + ws[3]) / (double)NTOT);
}

extern "C" void kernel_launch(void* const* d_in, const int* in_sizes, int n_in,
                              void* d_out, int out_size, void* d_ws, size_t ws_size,
                              hipStream_t stream) {
    const float* L   = (const float*)d_in[0];
    const float* R   = (const float*)d_in[1];
    const float* flm = (const float*)d_in[2];
    const float* frm = (const float*)d_in[3];
    const float* gt  = (const float*)d_in[4];
    float* part = (float*)d_ws;                // 7200 f32 partials, all written

    warp_loss_kernel<<<NWG, BLK, 0, stream>>>(L, R, flm, frm, gt, part);
    finalize_kernel<<<1, 256, 0, stream>>>(part, (float*)d_out);
}

// Round 26
// 89.309 us; speedup vs baseline: 1.1612x; 1.1612x over previous
//
#include <hip/hip_runtime.h>

constexpr int Bn = 8, Cn = 3, Hn = 720, Wn = 1280;
constexpr int HW = Hn * Wn;                    // 921600 px per image
constexpr long long NTOT = (long long)Bn * Cn * HW;

constexpr int BLK  = 256;
constexpr int TH   = 16, TW = 64;              // output tile 16x64 = 1024 px
constexpr int TCOL = Wn / TW;                  // 20 tile-cols
constexpr int TPI  = (Hn / TH) * TCOL;         // 900 tiles per image
constexpr int NWG  = 8 * TPI;                  // 7200 blocks; bid&7 = image/XCD
constexpr int PXT  = (TH * TW) / BLK;          // 4 px per thread
constexpr int WR   = 24;                       // window rows: Y-4 .. Y+19 (border-replicated)
constexpr int WC   = 84;                       // window cols: XS-4 .. XS+79
constexpr int F4W  = WC / 4;                   // 21 f4 per window row
constexpr int F4P  = WR * F4W;                 // 504 f4 slots per plane
constexpr int NF4  = 2 * F4P;                  // 1008 slots (L+R planes)
constexpr int PSE  = 2048;                     // plane stride (elements/dwords)

typedef float f4 __attribute__((ext_vector_type(4)));

__device__ __forceinline__ float lo16(unsigned w) { return __uint_as_float(w << 16); }
__device__ __forceinline__ float hi16(unsigned w) { return __uint_as_float(w & 0xffff0000u); }
__device__ __forceinline__ float bfv(unsigned short h) { return __uint_as_float((unsigned)h << 16); }

__global__ __launch_bounds__(256) void warp_loss_kernel(
        const float* __restrict__ L, const float* __restrict__ R,
        const float* __restrict__ Flm, const float* __restrict__ Frm,
        const float* __restrict__ G, float* __restrict__ part) {
    // Channel-packed windows: ch0|ch1 as bf16 pairs in one dword -> one
    // ds_read_b32 serves a tap for TWO channels (taps are channel-invariant).
    // 16 LDS reads/px vs 24. All 3 channels staged once (24.6KB, single
    // buffer) -> ONE barrier total. Plain per-block partial store (no atomic).
    const int b    = blockIdx.x & 7;
    const int t    = blockIdx.x >> 3;          // [0, 900)
    const int trow = t / TCOL;
    const int tcol = t - trow * TCOL;
    const int Y    = trow * TH;
    const int XS   = tcol * TW;
    const int tid  = (int)threadIdx.x;

    const float* __restrict__ Lb = L + (size_t)b * Cn * HW;
    const float* __restrict__ Rb = R + (size_t)b * Cn * HW;
    const float* __restrict__ Gb = G + (size_t)b * Cn * HW;
    const float* __restrict__ fl = Flm + (size_t)b * 2 * HW;  // [0,HW)=x, [HW,2HW)=y
    const float* __restrict__ fr = Frm + (size_t)b * 2 * HW;

    __shared__ unsigned       pk[2 * PSE];     // 16 KB: packed ch0(lo)|ch1(hi), L/R planes
    __shared__ unsigned short w2[2 * PSE];     // 8 KB: ch2 bf16, L/R planes
    __shared__ float wsum[4];

    // ---- staging slot geometry (channel-invariant); tail threads clamp ----
    int soff[4], dstE[4];
    #pragma unroll
    for (int k = 0; k < 4; ++k) {
        const int s  = min(k * BLK + tid, NF4 - 1);
        const int pl = (s >= F4P) ? 1 : 0;
        const int f  = s - pl * F4P;
        const int wr = f / F4W;
        const int c4 = f - wr * F4W;
        const int ys = min(max(Y - 4 + wr, 0), Hn - 1);
        const int xw = min(max(XS - 4 + c4 * 4, 0), Wn - 4);  // 16B-aligned, in-bounds
        soff[k] = ys * Wn + xw;
        dstE[k] = pl * PSE + wr * WC + c4 * 4; // element/dword idx, multiple of 4
    }

    // ---- prologue: stage ALL 3 channels (12 f4 loads) ----
    f4 c0[4], c1[4], c2[4];
    #pragma unroll
    for (int k = 0; k < 4; ++k) {
        const float* base = (dstE[k] >= PSE) ? Rb : Lb;
        c0[k] = *reinterpret_cast<const f4*>(base + soff[k]);
        c1[k] = *reinterpret_cast<const f4*>(base + HW + soff[k]);
        c2[k] = *reinterpret_cast<const f4*>(base + 2 * HW + soff[k]);
    }

    // ---- gt loads (all channels) ----
    float g[Cn][PXT];
    #pragma unroll
    for (int c = 0; c < Cn; ++c)
        #pragma unroll
        for (int k = 0; k < PXT; ++k) {
            const int i = k * BLK + tid;
            g[c][k] = Gb[(size_t)c * HW + (Y + (i >> 6)) * Wn + XS + (i & 63)];
        }

    // ---- per-px tap state (channel-invariant), coalesced flow loads ----
    int   aL[PXT], aR[PXT];
    float lwx[PXT], lwy[PXT], rwx[PXT], rwy[PXT];
    #pragma unroll
    for (int k = 0; k < PXT; ++k) {
        const int i = k * BLK + tid;
        const int r = i >> 6, cm = i & 63;
        const int y = Y + r, x = XS + cm;
        const int p = y * Wn + x;
        {
            const float fx = fminf(fmaxf(fl[p],      -4.0f), 3.99951171875f);
            const float fy = fminf(fmaxf(fl[HW + p], -4.0f), 3.99951171875f);
            const float xc = fminf(fmaxf((float)x + fx, 0.f), (float)(Wn - 1));
            const float yc = fminf(fmaxf((float)y + fy, 0.f), (float)(Hn - 1));
            const float x0f = floorf(xc), y0f = floorf(yc);
            lwx[k] = xc - x0f;  lwy[k] = yc - y0f;
            aL[k] = ((int)y0f - (Y - 4)) * WC + ((int)x0f - (XS - 4));
        }
        {
            const float fx = fminf(fmaxf(fr[p],      -4.0f), 3.99951171875f);
            const float fy = fminf(fmaxf(fr[HW + p], -4.0f), 3.99951171875f);
            const float xc = fminf(fmaxf((float)x + fx, 0.f), (float)(Wn - 1));
            const float yc = fminf(fmaxf((float)y + fy, 0.f), (float)(Hn - 1));
            const float x0f = floorf(xc), y0f = floorf(yc);
            rwx[k] = xc - x0f;  rwy[k] = yc - y0f;
            aR[k] = PSE + ((int)y0f - (Y - 4)) * WC + ((int)x0f - (XS - 4));
        }
    }

    // ---- pack + write windows: ch01 as dword pairs (16B), ch2 bf16 (8B) ----
    #pragma unroll
    for (int k = 0; k < 4; ++k) {
        unsigned dw0, dw1, dw2, dw3;
        asm("v_cvt_pk_bf16_f32 %0, %1, %2" : "=v"(dw0) : "v"(c0[k][0]), "v"(c1[k][0]));
        asm("v_cvt_pk_bf16_f32 %0, %1, %2" : "=v"(dw1) : "v"(c0[k][1]), "v"(c1[k][1]));
        asm("v_cvt_pk_bf16_f32 %0, %1, %2" : "=v"(dw2) : "v"(c0[k][2]), "v"(c1[k][2]));
        asm("v_cvt_pk_bf16_f32 %0, %1, %2" : "=v"(dw3) : "v"(c0[k][3]), "v"(c1[k][3]));
        uint4 u; u.x = dw0; u.y = dw1; u.z = dw2; u.w = dw3;
        *reinterpret_cast<uint4*>(&pk[dstE[k]]) = u;   // 16B aligned (dstE mult of 4)
        unsigned h0, h1;
        asm("v_cvt_pk_bf16_f32 %0, %1, %2" : "=v"(h0) : "v"(c2[k][0]), "v"(c2[k][1]));
        asm("v_cvt_pk_bf16_f32 %0, %1, %2" : "=v"(h1) : "v"(c2[k][2]), "v"(c2[k][3]));
        uint2 v; v.x = h0; v.y = h1;
        *reinterpret_cast<uint2*>(&w2[dstE[k]]) = v;   // 8B aligned
    }
    __syncthreads();                           // the ONLY barrier

    // ---- sample all 3 channels, both directions: pure LDS + VALU ----
    float local = 0.f;
    #pragma unroll
    for (int k = 0; k < PXT; ++k) {
        {   // L direction
            const int a = aL[k];
            const float wx = lwx[k], wy = lwy[k];
            const unsigned t0 = pk[a],      t1 = pk[a + 1];
            const unsigned b0 = pk[a + WC], b1 = pk[a + WC + 1];
            // ch0 (lo halves)
            float top = fmaf(wx, lo16(t1) - lo16(t0), lo16(t0));
            float bot = fmaf(wx, lo16(b1) - lo16(b0), lo16(b0));
            local += fabsf(fmaf(wy, bot - top, top) - g[0][k]);
            // ch1 (hi halves)
            top = fmaf(wx, hi16(t1) - hi16(t0), hi16(t0));
            bot = fmaf(wx, hi16(b1) - hi16(b0), hi16(b0));
            local += fabsf(fmaf(wy, bot - top, top) - g[1][k]);
            // ch2 (bf16 scalar)
            const float v00 = bfv(w2[a]),      v01 = bfv(w2[a + 1]);
            const float v10 = bfv(w2[a + WC]), v11 = bfv(w2[a + WC + 1]);
            top = fmaf(wx, v01 - v00, v00);
            bot = fmaf(wx, v11 - v10, v10);
            local += fabsf(fmaf(wy, bot - top, top) - g[2][k]);
        }
        {   // R direction
            const int a = aR[k];
            const float wx = rwx[k], wy = rwy[k];
            const unsigned t0 = pk[a],      t1 = pk[a + 1];
            const unsigned b0 = pk[a + WC], b1 = pk[a + WC + 1];
            float top = fmaf(wx, lo16(t1) - lo16(t0), lo16(t0));
            float bot = fmaf(wx, lo16(b1) - lo16(b0), lo16(b0));
            local += fabsf(fmaf(wy, bot - top, top) - g[0][k]);
            top = fmaf(wx, hi16(t1) - hi16(t0), hi16(t0));
            bot = fmaf(wx, hi16(b1) - hi16(b0), hi16(b0));
            local += fabsf(fmaf(wy, bot - top, top) - g[1][k]);
            const float v00 = bfv(w2[a]),      v01 = bfv(w2[a + 1]);
            const float v10 = bfv(w2[a + WC]), v11 = bfv(w2[a + WC + 1]);
            top = fmaf(wx, v01 - v00, v00);
            bot = fmaf(wx, v11 - v10, v10);
            local += fabsf(fmaf(wy, bot - top, top) - g[2][k]);
        }
    }

    // wave(64) shuffle reduce -> LDS cross-wave -> one plain store per block
    #pragma unroll
    for (int off = 32; off > 0; off >>= 1)
        local += __shfl_down(local, off, 64);

    const int lane = tid & 63;
    const int wid  = tid >> 6;
    if (lane == 0) wsum[wid] = local;
    __syncthreads();
    if (tid == 0)
        part[blockIdx.x] = wsum[0] + wsum[1] + wsum[2] + wsum[3];
}

__global__ __launch_bounds__(256) void finalize_kernel(
        const float* __restrict__ part, float* __restrict__ out) {
    double s = 0.0;
    for (int i = (int)threadIdx.x; i < NWG; i += 256)
        s += (double)part[i];
    #pragma unroll
    for (int off = 32; off > 0; off >>= 1)
        s += __shfl_down(s, off, 64);
    __shared__ double ws[4];
    const int lane = threadIdx.x & 63;
    const int wid  = threadIdx.x >> 6;
    if (lane == 0) ws[wid] = s;
    __syncthreads();
    if (threadIdx.x == 0)
        out[0] = (float)((ws[0] + ws[1] + ws[2] + ws[3]) / (double)NTOT);
}

extern "C" void kernel_launch(void* const* d_in, const int* in_sizes, int n_in,
                              void* d_out, int out_size, void* d_ws, size_t ws_size,
                              hipStream_t stream) {
    const float* L   = (const float*)d_in[0];
    const float* R   = (const float*)d_in[1];
    const float* flm = (const float*)d_in[2];
    const float* frm = (const float*)d_in[3];
    const float* gt  = (const float*)d_in[4];
    float* part = (float*)d_ws;                // 7200 f32 partials, all written

    warp_loss_kernel<<<NWG, BLK, 0, stream>>>(L, R, flm, frm, gt, part);
    finalize_kernel<<<1, 256, 0, stream>>>(part, (float*)d_out);
}